// Round 2
// baseline (1126.841 us; speedup 1.0000x reference)
//
#include <hip/hip_runtime.h>

typedef unsigned int u32;
typedef unsigned short u16;
typedef __bf16 bf16x8 __attribute__((ext_vector_type(8)));
typedef float f32x4 __attribute__((ext_vector_type(4)));

#define B_ 4
#define T_ 1024
#define C_ 1024
#define NH_ 16
#define L_ 512
#define DHR_ 64
#define FF_ 4096

__device__ __forceinline__ float bf2f(u16 u) {
  union { u32 i; float f; } v; v.i = ((u32)u) << 16; return v.f;
}
__device__ __forceinline__ u16 f2bf(float f) {
  union { float f; u32 i; } v; v.f = f;
  u32 r = (v.i + 0x7FFFu + ((v.i >> 16) & 1u)) >> 16;
  return (u16)r;
}
__device__ __forceinline__ void unpack8(uint4 v, float* dst) {
  dst[0] = bf2f((u16)(v.x & 0xffff)); dst[1] = bf2f((u16)(v.x >> 16));
  dst[2] = bf2f((u16)(v.y & 0xffff)); dst[3] = bf2f((u16)(v.y >> 16));
  dst[4] = bf2f((u16)(v.z & 0xffff)); dst[5] = bf2f((u16)(v.z >> 16));
  dst[6] = bf2f((u16)(v.w & 0xffff)); dst[7] = bf2f((u16)(v.w >> 16));
}

// ---------------------------------------------------------------------------
// Weight transpose + f32->bf16 convert: in f32 [R,C] -> out bf16 [C,R]
// ---------------------------------------------------------------------------
__global__ void transpose_kernel(const float* __restrict__ in, u16* __restrict__ outp,
                                 int R, int C) {
  __shared__ float tile[32][33];
  int bx = blockIdx.x * 32;  // col block
  int by = blockIdx.y * 32;  // row block
  int tx = threadIdx.x, ty = threadIdx.y;
  for (int i = ty; i < 32; i += 8)
    tile[i][tx] = in[(size_t)(by + i) * C + bx + tx];
  __syncthreads();
  for (int i = ty; i < 32; i += 8)
    outp[(size_t)(bx + i) * R + by + tx] = f2bf(tile[tx][i]);
}

// ---------------------------------------------------------------------------
// RMSNorm: row-per-block, C=1024, f32 in, f32 weight, bf16 out
// ---------------------------------------------------------------------------
__global__ __launch_bounds__(256) void rmsnorm_kernel(const float* __restrict__ xin,
                                                      const float* __restrict__ w,
                                                      u16* __restrict__ outp) {
  const int row = blockIdx.x;
  const int tid = threadIdx.x;
  const float* xp = xin + (size_t)row * C_;
  float v[4];
#pragma unroll
  for (int i = 0; i < 4; i++) v[i] = xp[tid + 256 * i];
  float ss = v[0] * v[0] + v[1] * v[1] + v[2] * v[2] + v[3] * v[3];
#pragma unroll
  for (int o = 32; o > 0; o >>= 1) ss += __shfl_down(ss, o, 64);
  __shared__ float red[4];
  if ((tid & 63) == 0) red[tid >> 6] = ss;
  __syncthreads();
  ss = red[0] + red[1] + red[2] + red[3];
  float scale = rsqrtf(ss * (1.0f / 1024.0f) + 1e-6f);
  u16* op = outp + (size_t)row * C_;
#pragma unroll
  for (int i = 0; i < 4; i++)
    op[tid + 256 * i] = f2bf(v[i] * scale * w[tid + 256 * i]);
}

// ---------------------------------------------------------------------------
// MFMA GEMM: C[M,N] = A[M,K] @ B[K,N] (+bias, +epilogue), B given TRANSPOSED
// A bf16 [.,lda], BT bf16 [N,K] row-major, bias f32.
// 64x64 tile, BK=32, 256 threads = 4 waves.
// EPI: 0 bf16 out | 1 f32 out | 2 bf16 out + gelu | 3 f32 out + f32 resid
// ---------------------------------------------------------------------------
#define BM 64
#define BN 64
#define BKK 32
#define SA 40  // padded LDS stride in bf16 elems (80 B, 16B-aligned)

template<int EPI>
__global__ __launch_bounds__(256) void gemm_bt(
    const u16* __restrict__ A, int lda, int aoff,
    const u16* __restrict__ BT, const float* __restrict__ bias,
    const float* __restrict__ resid, void* __restrict__ out,
    int M, int N, int K) {
  __shared__ __align__(16) u16 As[BM * SA];
  __shared__ __align__(16) u16 Bs[BN * SA];
  const int tid = threadIdx.x;
  const int wave = tid >> 6, lane = tid & 63;
  const int quad = lane >> 4, l15 = lane & 15;
  const int m0 = blockIdx.x * BM, n0 = blockIdx.y * BN;
  const int srow = tid >> 2, sseg = tid & 3;

  f32x4 acc[4] = {};
  const u16* aptr = A + (size_t)(m0 + srow) * lda + aoff + sseg * 8;
  const u16* bptr = BT + (size_t)(n0 + srow) * K + sseg * 8;

  for (int k0 = 0; k0 < K; k0 += BKK) {
    uint4 av = *(const uint4*)(aptr + k0);
    uint4 bv = *(const uint4*)(bptr + k0);
    __syncthreads();
    *(uint4*)&As[srow * SA + sseg * 8] = av;
    *(uint4*)&Bs[srow * SA + sseg * 8] = bv;
    __syncthreads();
    bf16x8 a = *(const bf16x8*)&As[(wave * 16 + l15) * SA + quad * 8];
#pragma unroll
    for (int nt = 0; nt < 4; nt++) {
      bf16x8 b = *(const bf16x8*)&Bs[(nt * 16 + l15) * SA + quad * 8];
      acc[nt] = __builtin_amdgcn_mfma_f32_16x16x32_bf16(a, b, acc[nt], 0, 0, 0);
    }
  }
  // C/D layout (m89/m91-verified): col = lane&15, row = quad*4 + reg
#pragma unroll
  for (int nt = 0; nt < 4; nt++) {
    int gn = n0 + nt * 16 + l15;
    float bvv = bias[gn];
#pragma unroll
    for (int i = 0; i < 4; i++) {
      int gm = m0 + wave * 16 + quad * 4 + i;
      size_t oidx = (size_t)gm * N + gn;
      float v = acc[nt][i] + bvv;
      if (EPI == 2) {
        float x = v;
        v = 0.5f * x * (1.0f + tanhf(0.7978845608028654f * (x + 0.044715f * x * x * x)));
      }
      if (EPI == 3) v += resid[oidx];
      if (EPI == 1 || EPI == 3) ((float*)out)[oidx] = v;
      else ((u16*)out)[oidx] = f2bf(v);
    }
  }
}

// ---------------------------------------------------------------------------
// RoPE + head assembly: build Qf/Kf [B,NH,T,128] bf16.
// Qf[.,h,t,0:64]  = q[b,t,h*64+d];  Qf[.,h,t,64+d] = rope_c1024(qr_pre)[h*64+d]
// Kf[.,h,t,0:64]  = k part of kv;   Kf[.,h,t,64+d] = rope_c64(kr_pre)[d]
// ---------------------------------------------------------------------------
__global__ __launch_bounds__(256) void rope_build(
    const u16* __restrict__ qb, const float* __restrict__ qr_pre,
    const u16* __restrict__ kvb, const float* __restrict__ kr_pre,
    u16* __restrict__ Qf, u16* __restrict__ Kf) {
  const int bt = blockIdx.x;
  const int b = bt >> 10, t = bt & 1023;
  const float freq = (float)(t + 1);
  for (int idx = threadIdx.x; idx < 2048; idx += 256) {
    const int h = idx >> 7, d = idx & 127;
    const size_t dst = (((size_t)(b * 16 + h)) * T_ + t) * 128 + d;
    u16 qv, kvv;
    if (d < 64) {
      qv = qb[(size_t)bt * C_ + h * 64 + d];
      kvv = kvb[(size_t)bt * 2048 + h * 64 + d];
    } else {
      const int dd = d - 64;
      {
        const int g = h * 64 + dd;
        const int p = g >> 1;
        const float theta = __expf(-(float)(2 * p) * (9.210340372f / 1024.0f));
        float s, c;
        sincosf(freq * theta, &s, &c);
        const float x0 = qr_pre[(size_t)bt * 1024 + (p << 1)];
        const float x1 = qr_pre[(size_t)bt * 1024 + (p << 1) + 1];
        qv = f2bf((g & 1) ? (x1 * c + x0 * s) : (x0 * c - x1 * s));
      }
      {
        const int p = dd >> 1;
        const float theta = __expf(-(float)(2 * p) * (9.210340372f / 64.0f));
        float s, c;
        sincosf(freq * theta, &s, &c);
        const float x0 = kr_pre[(size_t)bt * 64 + (p << 1)];
        const float x1 = kr_pre[(size_t)bt * 64 + (p << 1) + 1];
        kvv = f2bf((dd & 1) ? (x1 * c + x0 * s) : (x0 * c - x1 * s));
      }
    }
    Qf[dst] = qv;
    Kf[dst] = kvv;
  }
}

// ---------------------------------------------------------------------------
// Flash attention: block = (b, h, 32-row q-tile), 256 threads.
// Online softmax, fp32, causal. scale = 1/sqrt(64). V read from kv buffer.
// Output written directly in [B,T,C] layout (head-interleaved), bf16.
// ---------------------------------------------------------------------------
__global__ __launch_bounds__(256) void attn_kernel(
    const u16* __restrict__ Qf, const u16* __restrict__ Kf,
    const u16* __restrict__ kvbuf, u16* __restrict__ attn_o) {
  __shared__ float Qt[32][132];
  __shared__ float Kt[32][132];
  __shared__ float Vt[32][64];
  __shared__ float Sm[32][33];
  __shared__ float mst[32], lst[32], ast[32];

  const int tid = threadIdx.x;
  const int qt = blockIdx.x & 31;
  const int h = (blockIdx.x >> 5) & 15;
  const int b = blockIdx.x >> 9;
  const int q0 = qt * 32;
  const size_t bh = (size_t)(b * 16 + h);

  const int r = tid >> 3;  // 0..31 row handled by this thread
  const int cb = tid & 7;  // column base

  {  // stage Q tile (fp32 in LDS)
    const int d0 = cb * 16;
    const uint4* src = (const uint4*)&Qf[(bh * T_ + q0 + r) * 128 + d0];
    uint4 v0 = src[0], v1 = src[1];
    float tmp[16];
    unpack8(v0, tmp); unpack8(v1, tmp + 8);
#pragma unroll
    for (int i = 0; i < 16; i++) Qt[r][d0 + i] = tmp[i];
  }
  if (tid < 32) { mst[tid] = -3.0e38f; lst[tid] = 0.0f; }
  float o[8] = {0, 0, 0, 0, 0, 0, 0, 0};
  __syncthreads();

  for (int kt = 0; kt <= qt; kt++) {
    {  // stage K,V tiles
      const int d0 = cb * 16;
      const uint4* ks = (const uint4*)&Kf[(bh * T_ + kt * 32 + r) * 128 + d0];
      uint4 k0v = ks[0], k1v = ks[1];
      float tmp[16];
      unpack8(k0v, tmp); unpack8(k1v, tmp + 8);
#pragma unroll
      for (int i = 0; i < 16; i++) Kt[r][d0 + i] = tmp[i];
      const int vd0 = cb * 8;
      uint4 vv = *(const uint4*)&kvbuf[((size_t)(b * T_) + kt * 32 + r) * 2048 + 1024 + h * 64 + vd0];
      float vt[8];
      unpack8(vv, vt);
#pragma unroll
      for (int i = 0; i < 8; i++) Vt[r][vd0 + i] = vt[i];
    }
    __syncthreads();
    // S = Q K^T  (thread: row r, cols cb+8j)
    float s0 = 0, s1 = 0, s2 = 0, s3 = 0;
    for (int d = 0; d < 128; d += 4) {
      float4 qv = *(const float4*)&Qt[r][d];
      float4 ka = *(const float4*)&Kt[cb][d];
      float4 kb = *(const float4*)&Kt[cb + 8][d];
      float4 kc = *(const float4*)&Kt[cb + 16][d];
      float4 kd = *(const float4*)&Kt[cb + 24][d];
      s0 += qv.x * ka.x + qv.y * ka.y + qv.z * ka.z + qv.w * ka.w;
      s1 += qv.x * kb.x + qv.y * kb.y + qv.z * kb.z + qv.w * kb.w;
      s2 += qv.x * kc.x + qv.y * kc.y + qv.z * kc.z + qv.w * kc.w;
      s3 += qv.x * kd.x + qv.y * kd.y + qv.z * kd.z + qv.w * kd.w;
    }
    float sv[4] = {s0, s1, s2, s3};
#pragma unroll
    for (int j = 0; j < 4; j++) {
      int c = cb + 8 * j;
      float s = sv[j] * 0.125f;
      if (kt * 32 + c > q0 + r) s = -3.0e38f;  // causal mask -> exp() == 0
      Sm[r][c] = s;
    }
    __syncthreads();
    if (tid < 32) {  // online softmax row update
      float mold = mst[tid];
      float mx = mold;
      for (int c = 0; c < 32; c++) mx = fmaxf(mx, Sm[tid][c]);
      float alpha = __expf(mold - mx);
      float sum = 0.0f;
      for (int c = 0; c < 32; c++) {
        float p = __expf(Sm[tid][c] - mx);
        Sm[tid][c] = p;
        sum += p;
      }
      lst[tid] = lst[tid] * alpha + sum;
      mst[tid] = mx;
      ast[tid] = alpha;
    }
    __syncthreads();
    {  // O = O*alpha + P @ V   (thread: row r, out cols cb*8..cb*8+7)
      float alpha = ast[r];
#pragma unroll
      for (int i = 0; i < 8; i++) o[i] *= alpha;
      const int c0 = cb * 8;
      for (int kc = 0; kc < 32; kc++) {
        float p = Sm[r][kc];
        float4 v0 = *(const float4*)&Vt[kc][c0];
        float4 v1 = *(const float4*)&Vt[kc][c0 + 4];
        o[0] += p * v0.x; o[1] += p * v0.y; o[2] += p * v0.z; o[3] += p * v0.w;
        o[4] += p * v1.x; o[5] += p * v1.y; o[6] += p * v1.z; o[7] += p * v1.w;
      }
    }
    __syncthreads();
  }
  float linv = 1.0f / lst[r];
  const int c0 = cb * 8;
  u16 ov[8];
#pragma unroll
  for (int i = 0; i < 8; i++) ov[i] = f2bf(o[i] * linv);
  uint4 pack;
  pack.x = (u32)ov[0] | ((u32)ov[1] << 16);
  pack.y = (u32)ov[2] | ((u32)ov[3] << 16);
  pack.z = (u32)ov[4] | ((u32)ov[5] << 16);
  pack.w = (u32)ov[6] | ((u32)ov[7] << 16);
  *(uint4*)&attn_o[((size_t)(b * T_) + q0 + r) * C_ + h * 64 + c0] = pack;
}

// ---------------------------------------------------------------------------
extern "C" void kernel_launch(void* const* d_in, const int* in_sizes, int n_in,
                              void* d_out, int out_size, void* d_ws, size_t ws_size,
                              hipStream_t stream) {
  const float* x = (const float*)d_in[0];
  const float* rms1 = (const float*)d_in[1];
  const float* rms2 = (const float*)d_in[2];
  const float* W_dkv = (const float*)d_in[3];
  const float* b_dkv = (const float*)d_in[4];
  const float* W_kr = (const float*)d_in[5];
  const float* b_kr = (const float*)d_in[6];
  const float* W_qr = (const float*)d_in[7];
  const float* b_qr = (const float*)d_in[8];
  const float* W_kv = (const float*)d_in[9];
  const float* b_kv = (const float*)d_in[10];
  const float* W_q = (const float*)d_in[11];
  const float* b_q = (const float*)d_in[12];
  const float* W_o = (const float*)d_in[13];
  const float* b_o = (const float*)d_in[14];
  const float* W_f1 = (const float*)d_in[15];
  const float* b_f1 = (const float*)d_in[16];
  const float* W_f2 = (const float*)d_in[17];
  const float* b_f2 = (const float*)d_in[18];
  float* out = (float*)d_out;

  char* ws = (char*)d_ws;
  size_t off = 0;
  auto alloc = [&](size_t bytes) -> void* {
    void* p = ws + off;
    off += (bytes + 255) & ~(size_t)255;
    return p;
  };
  u16* WT_dkv = (u16*)alloc((size_t)1024 * 1024 * 2);
  u16* WT_kr  = (u16*)alloc((size_t)64 * 1024 * 2);
  u16* WT_qr  = (u16*)alloc((size_t)1024 * 1024 * 2);
  u16* WT_kv  = (u16*)alloc((size_t)2048 * 512 * 2);
  u16* WT_q   = (u16*)alloc((size_t)1024 * 512 * 2);
  u16* WT_o   = (u16*)alloc((size_t)1024 * 1024 * 2);
  u16* WT_f1  = (u16*)alloc((size_t)4096 * 1024 * 2);
  u16* WT_f2  = (u16*)alloc((size_t)1024 * 4096 * 2);
  u16* xn1    = (u16*)alloc((size_t)4096 * 1024 * 2);
  u16* comp   = (u16*)alloc((size_t)4096 * 1024 * 2);
  float* kr_pre = (float*)alloc((size_t)4096 * 64 * 4);
  float* qr_pre = (float*)alloc((size_t)4096 * 1024 * 4);
  u16* kvbuf  = (u16*)alloc((size_t)4096 * 2048 * 2);
  u16* qbuf   = (u16*)alloc((size_t)4096 * 1024 * 2);
  u16* Qf     = (u16*)alloc((size_t)64 * 1024 * 128 * 2);
  u16* Kf     = (u16*)alloc((size_t)64 * 1024 * 128 * 2);
  u16* attn_o = (u16*)alloc((size_t)4096 * 1024 * 2);
  float* hbuf = (float*)alloc((size_t)4096 * 1024 * 4);
  u16* hn     = (u16*)alloc((size_t)4096 * 1024 * 2);
  u16* hid    = (u16*)alloc((size_t)4096 * 4096 * 2);

  dim3 tb(32, 8);
  // weight transposes+convert [R,C] f32 -> [C,R] bf16; grid = (C/32, R/32)
  transpose_kernel<<<dim3(32, 32), tb, 0, stream>>>(W_dkv, WT_dkv, 1024, 1024);
  transpose_kernel<<<dim3(2, 32), tb, 0, stream>>>(W_kr, WT_kr, 1024, 64);
  transpose_kernel<<<dim3(32, 32), tb, 0, stream>>>(W_qr, WT_qr, 1024, 1024);
  transpose_kernel<<<dim3(64, 16), tb, 0, stream>>>(W_kv, WT_kv, 512, 2048);
  transpose_kernel<<<dim3(32, 16), tb, 0, stream>>>(W_q, WT_q, 512, 1024);
  transpose_kernel<<<dim3(32, 32), tb, 0, stream>>>(W_o, WT_o, 1024, 1024);
  transpose_kernel<<<dim3(128, 32), tb, 0, stream>>>(W_f1, WT_f1, 1024, 4096);
  transpose_kernel<<<dim3(32, 128), tb, 0, stream>>>(W_f2, WT_f2, 4096, 1024);

  // xn1 = rms_norm(x, rms1)
  rmsnorm_kernel<<<4096, 256, 0, stream>>>(x, rms1, xn1);

  // comp = xn1 @ W_dkv + b_dkv            [4096,1024]
  gemm_bt<0><<<dim3(64, 16), 256, 0, stream>>>(xn1, 1024, 0, WT_dkv, b_dkv, nullptr, comp, 4096, 1024, 1024);
  // kr_pre = comp @ W_kr + b_kr (f32)     [4096,64]
  gemm_bt<1><<<dim3(64, 1), 256, 0, stream>>>(comp, 1024, 0, WT_kr, b_kr, nullptr, kr_pre, 4096, 64, 1024);
  // qr_pre = comp @ W_qr + b_qr (f32)     [4096,1024]
  gemm_bt<1><<<dim3(64, 16), 256, 0, stream>>>(comp, 1024, 0, WT_qr, b_qr, nullptr, qr_pre, 4096, 1024, 1024);
  // kv = cKV @ W_kv + b_kv                [4096,2048]
  gemm_bt<0><<<dim3(64, 32), 256, 0, stream>>>(comp, 1024, 0, WT_kv, b_kv, nullptr, kvbuf, 4096, 2048, 512);
  // q = cq @ W_q + b_q                    [4096,1024]
  gemm_bt<0><<<dim3(64, 16), 256, 0, stream>>>(comp, 1024, 512, WT_q, b_q, nullptr, qbuf, 4096, 1024, 512);

  // Qf/Kf assembly + RoPE
  rope_build<<<4096, 256, 0, stream>>>(qbuf, qr_pre, kvbuf, kr_pre, Qf, Kf);

  // attention
  attn_kernel<<<B_ * NH_ * (T_ / 32), 256, 0, stream>>>(Qf, Kf, kvbuf, attn_o);

  // h = x + attn_o @ W_o + b_o (f32)
  gemm_bt<3><<<dim3(64, 16), 256, 0, stream>>>(attn_o, 1024, 0, WT_o, b_o, x, hbuf, 4096, 1024, 1024);

  // hn = rms_norm(h, rms2)
  rmsnorm_kernel<<<4096, 256, 0, stream>>>(hbuf, rms2, hn);

  // hid = gelu(hn @ W_f1 + b_f1)          [4096,4096]
  gemm_bt<2><<<dim3(64, 64), 256, 0, stream>>>(hn, 1024, 0, WT_f1, b_f1, nullptr, hid, 4096, 4096, 1024);
  // out = h + hid @ W_f2 + b_f2           [4096,1024] f32
  gemm_bt<3><<<dim3(64, 16), 256, 0, stream>>>(hid, 4096, 0, WT_f2, b_f2, hbuf, out, 4096, 1024, 4096);
}

// Round 3
// 577.121 us; speedup vs baseline: 1.9525x; 1.9525x over previous
//
#include <hip/hip_runtime.h>

typedef unsigned int u32;
typedef unsigned short u16;
typedef __bf16 bf16x8 __attribute__((ext_vector_type(8)));
typedef float f32x4 __attribute__((ext_vector_type(4)));

#define B_ 4
#define T_ 1024
#define C_ 1024
#define NH_ 16
#define L_ 512
#define DHR_ 64
#define FF_ 4096

__device__ __forceinline__ float bf2f(u16 u) {
  union { u32 i; float f; } v; v.i = ((u32)u) << 16; return v.f;
}
__device__ __forceinline__ u16 f2bf(float f) {
  union { float f; u32 i; } v; v.f = f;
  u32 r = (v.i + 0x7FFFu + ((v.i >> 16) & 1u)) >> 16;
  return (u16)r;
}

// ---------------------------------------------------------------------------
// Weight transpose + f32->bf16 convert: in f32 [R,C] -> out bf16 [C,R]
// ---------------------------------------------------------------------------
__global__ void transpose_kernel(const float* __restrict__ in, u16* __restrict__ outp,
                                 int R, int C) {
  __shared__ float tile[32][33];
  int bx = blockIdx.x * 32;  // col block
  int by = blockIdx.y * 32;  // row block
  int tx = threadIdx.x, ty = threadIdx.y;
  for (int i = ty; i < 32; i += 8)
    tile[i][tx] = in[(size_t)(by + i) * C + bx + tx];
  __syncthreads();
  for (int i = ty; i < 32; i += 8)
    outp[(size_t)(bx + i) * R + by + tx] = f2bf(tile[tx][i]);
}

// ---------------------------------------------------------------------------
// RMSNorm: row-per-block, C=1024, f32 in, f32 weight, bf16 out
// ---------------------------------------------------------------------------
__global__ __launch_bounds__(256) void rmsnorm_kernel(const float* __restrict__ xin,
                                                      const float* __restrict__ w,
                                                      u16* __restrict__ outp) {
  const int row = blockIdx.x;
  const int tid = threadIdx.x;
  const float* xp = xin + (size_t)row * C_;
  float v[4];
#pragma unroll
  for (int i = 0; i < 4; i++) v[i] = xp[tid + 256 * i];
  float ss = v[0] * v[0] + v[1] * v[1] + v[2] * v[2] + v[3] * v[3];
#pragma unroll
  for (int o = 32; o > 0; o >>= 1) ss += __shfl_down(ss, o, 64);
  __shared__ float red[4];
  if ((tid & 63) == 0) red[tid >> 6] = ss;
  __syncthreads();
  ss = red[0] + red[1] + red[2] + red[3];
  float scale = rsqrtf(ss * (1.0f / 1024.0f) + 1e-6f);
  u16* op = outp + (size_t)row * C_;
#pragma unroll
  for (int i = 0; i < 4; i++)
    op[tid + 256 * i] = f2bf(v[i] * scale * w[tid + 256 * i]);
}

// ---------------------------------------------------------------------------
// MFMA GEMM (unchanged from round 2): C = A @ B^T(+bias,+epi)
// EPI: 0 bf16 out | 1 f32 out | 2 bf16 out + gelu | 3 f32 out + f32 resid
// ---------------------------------------------------------------------------
#define BM 64
#define BN 64
#define BKK 32
#define SA 40

template<int EPI>
__global__ __launch_bounds__(256) void gemm_bt(
    const u16* __restrict__ A, int lda, int aoff,
    const u16* __restrict__ BT, const float* __restrict__ bias,
    const float* __restrict__ resid, void* __restrict__ out,
    int M, int N, int K) {
  __shared__ __align__(16) u16 As[BM * SA];
  __shared__ __align__(16) u16 Bs[BN * SA];
  const int tid = threadIdx.x;
  const int wave = tid >> 6, lane = tid & 63;
  const int quad = lane >> 4, l15 = lane & 15;
  const int m0 = blockIdx.x * BM, n0 = blockIdx.y * BN;
  const int srow = tid >> 2, sseg = tid & 3;

  f32x4 acc[4] = {};
  const u16* aptr = A + (size_t)(m0 + srow) * lda + aoff + sseg * 8;
  const u16* bptr = BT + (size_t)(n0 + srow) * K + sseg * 8;

  for (int k0 = 0; k0 < K; k0 += BKK) {
    uint4 av = *(const uint4*)(aptr + k0);
    uint4 bv = *(const uint4*)(bptr + k0);
    __syncthreads();
    *(uint4*)&As[srow * SA + sseg * 8] = av;
    *(uint4*)&Bs[srow * SA + sseg * 8] = bv;
    __syncthreads();
    bf16x8 a = *(const bf16x8*)&As[(wave * 16 + l15) * SA + quad * 8];
#pragma unroll
    for (int nt = 0; nt < 4; nt++) {
      bf16x8 b = *(const bf16x8*)&Bs[(nt * 16 + l15) * SA + quad * 8];
      acc[nt] = __builtin_amdgcn_mfma_f32_16x16x32_bf16(a, b, acc[nt], 0, 0, 0);
    }
  }
#pragma unroll
  for (int nt = 0; nt < 4; nt++) {
    int gn = n0 + nt * 16 + l15;
    float bvv = bias[gn];
#pragma unroll
    for (int i = 0; i < 4; i++) {
      int gm = m0 + wave * 16 + quad * 4 + i;
      size_t oidx = (size_t)gm * N + gn;
      float v = acc[nt][i] + bvv;
      if (EPI == 2) {
        float x = v;
        v = 0.5f * x * (1.0f + tanhf(0.7978845608028654f * (x + 0.044715f * x * x * x)));
      }
      if (EPI == 3) v += resid[oidx];
      if (EPI == 1 || EPI == 3) ((float*)out)[oidx] = v;
      else ((u16*)out)[oidx] = f2bf(v);
    }
  }
}

// ---------------------------------------------------------------------------
// RoPE + head assembly (unchanged): Qf/Kf [B,NH,T,128] bf16
// ---------------------------------------------------------------------------
__global__ __launch_bounds__(256) void rope_build(
    const u16* __restrict__ qb, const float* __restrict__ qr_pre,
    const u16* __restrict__ kvb, const float* __restrict__ kr_pre,
    u16* __restrict__ Qf, u16* __restrict__ Kf) {
  const int bt = blockIdx.x;
  const int b = bt >> 10, t = bt & 1023;
  const float freq = (float)(t + 1);
  for (int idx = threadIdx.x; idx < 2048; idx += 256) {
    const int h = idx >> 7, d = idx & 127;
    const size_t dst = (((size_t)(b * 16 + h)) * T_ + t) * 128 + d;
    u16 qv, kvv;
    if (d < 64) {
      qv = qb[(size_t)bt * C_ + h * 64 + d];
      kvv = kvb[(size_t)bt * 2048 + h * 64 + d];
    } else {
      const int dd = d - 64;
      {
        const int g = h * 64 + dd;
        const int p = g >> 1;
        const float theta = __expf(-(float)(2 * p) * (9.210340372f / 1024.0f));
        float s, c;
        sincosf(freq * theta, &s, &c);
        const float x0 = qr_pre[(size_t)bt * 1024 + (p << 1)];
        const float x1 = qr_pre[(size_t)bt * 1024 + (p << 1) + 1];
        qv = f2bf((g & 1) ? (x1 * c + x0 * s) : (x0 * c - x1 * s));
      }
      {
        const int p = dd >> 1;
        const float theta = __expf(-(float)(2 * p) * (9.210340372f / 64.0f));
        float s, c;
        sincosf(freq * theta, &s, &c);
        const float x0 = kr_pre[(size_t)bt * 64 + (p << 1)];
        const float x1 = kr_pre[(size_t)bt * 64 + (p << 1) + 1];
        kvv = f2bf((dd & 1) ? (x1 * c + x0 * s) : (x0 * c - x1 * s));
      }
    }
    Qf[dst] = qv;
    Kf[dst] = kvv;
  }
}

// ---------------------------------------------------------------------------
// MFMA flash attention. Block = (b, h, 64-row q-tile), 256 thr = 4 waves.
// Wave w owns q-rows [w*16, w*16+16). K-tiles of 64. Online softmax in regs
// on the MFMA C-layout (row=quad*4+i, col=l15; reduce across l15 lanes by
// shfl_xor). P goes C-layout -> A-layout through per-wave LDS (m120 pattern).
// V staged transposed (Vt[d][kpos]) so PV B-frags are contiguous b128 reads.
// ---------------------------------------------------------------------------
#define QSTR 136  // 128+8 pad
#define VSTR 72   // 64+8 pad

__global__ __launch_bounds__(256) void attn_mfma(
    const u16* __restrict__ Qf, const u16* __restrict__ Kf,
    const u16* __restrict__ kvbuf, u16* __restrict__ attn_o) {
  __shared__ __align__(16) u16 Qs[64 * QSTR];
  __shared__ __align__(16) u16 Ks[64 * QSTR];
  __shared__ __align__(16) u16 Vt[64 * VSTR];
  __shared__ __align__(16) u16 Ps[4][16 * VSTR];

  const int tid = threadIdx.x;
  const int wave = tid >> 6, lane = tid & 63;
  const int quad = lane >> 4, l15 = lane & 15;
  const int qt = blockIdx.x & 15;        // 16 q-tiles of 64
  const int h = (blockIdx.x >> 4) & 15;
  const int b = blockIdx.x >> 8;
  const int q0 = qt * 64;
  const size_t bh = (size_t)(b * 16 + h);

  {  // stage Q tile: thread covers rows {r, r+32}, 32B column segment
    const int r = tid >> 3, cs = (tid & 7) * 16;
    const u16* s0 = &Qf[(bh * T_ + q0 + r) * 128 + cs];
    const u16* s1 = &Qf[(bh * T_ + q0 + r + 32) * 128 + cs];
    *(uint4*)&Qs[r * QSTR + cs] = *(const uint4*)s0;
    *(uint4*)&Qs[r * QSTR + cs + 8] = *(const uint4*)(s0 + 8);
    *(uint4*)&Qs[(r + 32) * QSTR + cs] = *(const uint4*)s1;
    *(uint4*)&Qs[(r + 32) * QSTR + cs + 8] = *(const uint4*)(s1 + 8);
  }

  f32x4 acc_o[4] = {};
  float m_i[4], l_i[4];
#pragma unroll
  for (int i = 0; i < 4; i++) { m_i[i] = -3.0e38f; l_i[i] = 0.0f; }

  for (int kt = 0; kt <= qt; kt++) {
    __syncthreads();  // previous iteration's readers done with Ks/Vt
    {  // stage K tile (same pattern as Q)
      const int r = tid >> 3, cs = (tid & 7) * 16;
      const u16* s0 = &Kf[(bh * T_ + kt * 64 + r) * 128 + cs];
      const u16* s1 = &Kf[(bh * T_ + kt * 64 + r + 32) * 128 + cs];
      *(uint4*)&Ks[r * QSTR + cs] = *(const uint4*)s0;
      *(uint4*)&Ks[r * QSTR + cs + 8] = *(const uint4*)(s0 + 8);
      *(uint4*)&Ks[(r + 32) * QSTR + cs] = *(const uint4*)s1;
      *(uint4*)&Ks[(r + 32) * QSTR + cs + 8] = *(const uint4*)(s1 + 8);
      // stage V transposed: thread reads V[kpos][d0..d0+15], scatters to Vt
      const int kpos = tid >> 2, d0 = (tid & 3) * 16;
      const u16* vsrc = &kvbuf[((size_t)(b * T_) + kt * 64 + kpos) * 2048 + 1024 + h * 64 + d0];
      uint4 v0 = *(const uint4*)vsrc;
      uint4 v1 = *(const uint4*)(vsrc + 8);
      u16 tmp[16];
      *(uint4*)tmp = v0;
      *(uint4*)(tmp + 8) = v1;
#pragma unroll
      for (int j = 0; j < 16; j++) Vt[(d0 + j) * VSTR + kpos] = tmp[j];
    }
    __syncthreads();

    // S = Q K^T : 16 MFMAs -> acc_s[ng], C layout row=quad*4+i col=l15
    f32x4 acc_s[4] = {};
#pragma unroll
    for (int kc = 0; kc < 4; kc++) {
      bf16x8 a = *(const bf16x8*)&Qs[(wave * 16 + l15) * QSTR + kc * 32 + quad * 8];
#pragma unroll
      for (int ng = 0; ng < 4; ng++) {
        bf16x8 bb = *(const bf16x8*)&Ks[(ng * 16 + l15) * QSTR + kc * 32 + quad * 8];
        acc_s[ng] = __builtin_amdgcn_mfma_f32_16x16x32_bf16(a, bb, acc_s[ng], 0, 0, 0);
      }
    }

    // scale + causal mask (diagonal tile only)
    float sv[4][4];
#pragma unroll
    for (int ng = 0; ng < 4; ng++)
#pragma unroll
      for (int i = 0; i < 4; i++) {
        float s = acc_s[ng][i] * 0.125f;
        if (kt == qt && (ng * 16 + l15) > (wave * 16 + quad * 4 + i)) s = -3.0e38f;
        sv[ng][i] = s;
      }

    // online softmax: row stats live replicated across the 16 l15 lanes
    float alpha[4], mx[4];
#pragma unroll
    for (int i = 0; i < 4; i++) {
      float m = fmaxf(fmaxf(sv[0][i], sv[1][i]), fmaxf(sv[2][i], sv[3][i]));
#pragma unroll
      for (int off = 1; off < 16; off <<= 1) m = fmaxf(m, __shfl_xor(m, off, 64));
      float mn = fmaxf(m_i[i], m);
      alpha[i] = __expf(m_i[i] - mn);
      m_i[i] = mn;
      mx[i] = mn;
    }
    float rs[4] = {0.f, 0.f, 0.f, 0.f};
#pragma unroll
    for (int ng = 0; ng < 4; ng++)
#pragma unroll
      for (int i = 0; i < 4; i++) {
        float p = __expf(sv[ng][i] - mx[i]);
        rs[i] += p;
        Ps[wave][(quad * 4 + i) * VSTR + ng * 16 + l15] = f2bf(p);
      }
#pragma unroll
    for (int i = 0; i < 4; i++) {
      float r = rs[i];
#pragma unroll
      for (int off = 1; off < 16; off <<= 1) r += __shfl_xor(r, off, 64);
      l_i[i] = l_i[i] * alpha[i] + r;
      rs[i] = r;
    }

    // O = O*alpha + P @ V  (P from per-wave LDS in A layout; no barrier —
    // Ps is private to this wave, lgkmcnt ordering suffices)
#pragma unroll
    for (int ng = 0; ng < 4; ng++)
#pragma unroll
      for (int i = 0; i < 4; i++) acc_o[ng][i] *= alpha[i];
#pragma unroll
    for (int kc = 0; kc < 2; kc++) {
      bf16x8 a = *(const bf16x8*)&Ps[wave][l15 * VSTR + kc * 32 + quad * 8];
#pragma unroll
      for (int ng = 0; ng < 4; ng++) {
        bf16x8 bb = *(const bf16x8*)&Vt[(ng * 16 + l15) * VSTR + kc * 32 + quad * 8];
        acc_o[ng] = __builtin_amdgcn_mfma_f32_16x16x32_bf16(a, bb, acc_o[ng], 0, 0, 0);
      }
    }
  }

  // epilogue: normalize and write [B,T,C] bf16, head-interleaved
  float linv[4];
#pragma unroll
  for (int i = 0; i < 4; i++) linv[i] = 1.0f / l_i[i];
#pragma unroll
  for (int ng = 0; ng < 4; ng++)
#pragma unroll
    for (int i = 0; i < 4; i++) {
      const int qrow = q0 + wave * 16 + quad * 4 + i;
      attn_o[((size_t)(b * T_) + qrow) * C_ + h * 64 + ng * 16 + l15] =
          f2bf(acc_o[ng][i] * linv[i]);
    }
}

// ---------------------------------------------------------------------------
extern "C" void kernel_launch(void* const* d_in, const int* in_sizes, int n_in,
                              void* d_out, int out_size, void* d_ws, size_t ws_size,
                              hipStream_t stream) {
  const float* x = (const float*)d_in[0];
  const float* rms1 = (const float*)d_in[1];
  const float* rms2 = (const float*)d_in[2];
  const float* W_dkv = (const float*)d_in[3];
  const float* b_dkv = (const float*)d_in[4];
  const float* W_kr = (const float*)d_in[5];
  const float* b_kr = (const float*)d_in[6];
  const float* W_qr = (const float*)d_in[7];
  const float* b_qr = (const float*)d_in[8];
  const float* W_kv = (const float*)d_in[9];
  const float* b_kv = (const float*)d_in[10];
  const float* W_q = (const float*)d_in[11];
  const float* b_q = (const float*)d_in[12];
  const float* W_o = (const float*)d_in[13];
  const float* b_o = (const float*)d_in[14];
  const float* W_f1 = (const float*)d_in[15];
  const float* b_f1 = (const float*)d_in[16];
  const float* W_f2 = (const float*)d_in[17];
  const float* b_f2 = (const float*)d_in[18];
  float* out = (float*)d_out;

  char* ws = (char*)d_ws;
  size_t off = 0;
  auto alloc = [&](size_t bytes) -> void* {
    void* p = ws + off;
    off += (bytes + 255) & ~(size_t)255;
    return p;
  };
  u16* WT_dkv = (u16*)alloc((size_t)1024 * 1024 * 2);
  u16* WT_kr  = (u16*)alloc((size_t)64 * 1024 * 2);
  u16* WT_qr  = (u16*)alloc((size_t)1024 * 1024 * 2);
  u16* WT_kv  = (u16*)alloc((size_t)2048 * 512 * 2);
  u16* WT_q   = (u16*)alloc((size_t)1024 * 512 * 2);
  u16* WT_o   = (u16*)alloc((size_t)1024 * 1024 * 2);
  u16* WT_f1  = (u16*)alloc((size_t)4096 * 1024 * 2);
  u16* WT_f2  = (u16*)alloc((size_t)1024 * 4096 * 2);
  u16* xn1    = (u16*)alloc((size_t)4096 * 1024 * 2);
  u16* comp   = (u16*)alloc((size_t)4096 * 1024 * 2);
  float* kr_pre = (float*)alloc((size_t)4096 * 64 * 4);
  float* qr_pre = (float*)alloc((size_t)4096 * 1024 * 4);
  u16* kvbuf  = (u16*)alloc((size_t)4096 * 2048 * 2);
  u16* qbuf   = (u16*)alloc((size_t)4096 * 1024 * 2);
  u16* Qf     = (u16*)alloc((size_t)64 * 1024 * 128 * 2);
  u16* Kf     = (u16*)alloc((size_t)64 * 1024 * 128 * 2);
  u16* attn_o = (u16*)alloc((size_t)4096 * 1024 * 2);
  float* hbuf = (float*)alloc((size_t)4096 * 1024 * 4);
  u16* hn     = (u16*)alloc((size_t)4096 * 1024 * 2);
  u16* hid    = (u16*)alloc((size_t)4096 * 4096 * 2);

  dim3 tb(32, 8);
  transpose_kernel<<<dim3(32, 32), tb, 0, stream>>>(W_dkv, WT_dkv, 1024, 1024);
  transpose_kernel<<<dim3(2, 32), tb, 0, stream>>>(W_kr, WT_kr, 1024, 64);
  transpose_kernel<<<dim3(32, 32), tb, 0, stream>>>(W_qr, WT_qr, 1024, 1024);
  transpose_kernel<<<dim3(64, 16), tb, 0, stream>>>(W_kv, WT_kv, 512, 2048);
  transpose_kernel<<<dim3(32, 16), tb, 0, stream>>>(W_q, WT_q, 512, 1024);
  transpose_kernel<<<dim3(32, 32), tb, 0, stream>>>(W_o, WT_o, 1024, 1024);
  transpose_kernel<<<dim3(128, 32), tb, 0, stream>>>(W_f1, WT_f1, 1024, 4096);
  transpose_kernel<<<dim3(32, 128), tb, 0, stream>>>(W_f2, WT_f2, 4096, 1024);

  rmsnorm_kernel<<<4096, 256, 0, stream>>>(x, rms1, xn1);

  gemm_bt<0><<<dim3(64, 16), 256, 0, stream>>>(xn1, 1024, 0, WT_dkv, b_dkv, nullptr, comp, 4096, 1024, 1024);
  gemm_bt<1><<<dim3(64, 1), 256, 0, stream>>>(comp, 1024, 0, WT_kr, b_kr, nullptr, kr_pre, 4096, 64, 1024);
  gemm_bt<1><<<dim3(64, 16), 256, 0, stream>>>(comp, 1024, 0, WT_qr, b_qr, nullptr, qr_pre, 4096, 1024, 1024);
  gemm_bt<0><<<dim3(64, 32), 256, 0, stream>>>(comp, 1024, 0, WT_kv, b_kv, nullptr, kvbuf, 4096, 2048, 512);
  gemm_bt<0><<<dim3(64, 16), 256, 0, stream>>>(comp, 1024, 512, WT_q, b_q, nullptr, qbuf, 4096, 1024, 512);

  rope_build<<<4096, 256, 0, stream>>>(qbuf, qr_pre, kvbuf, kr_pre, Qf, Kf);

  attn_mfma<<<B_ * NH_ * (T_ / 64), 256, 0, stream>>>(Qf, Kf, kvbuf, attn_o);

  gemm_bt<3><<<dim3(64, 16), 256, 0, stream>>>(attn_o, 1024, 0, WT_o, b_o, x, hbuf, 4096, 1024, 1024);

  rmsnorm_kernel<<<4096, 256, 0, stream>>>(hbuf, rms2, hn);

  gemm_bt<2><<<dim3(64, 64), 256, 0, stream>>>(hn, 1024, 0, WT_f1, b_f1, nullptr, hid, 4096, 4096, 1024);
  gemm_bt<3><<<dim3(64, 16), 256, 0, stream>>>(hid, 4096, 0, WT_f2, b_f2, hbuf, out, 4096, 1024, 4096);
}